// Round 2
// baseline (87.527 us; speedup 1.0000x reference)
//
#include <hip/hip_runtime.h>

// Geometric product over 3D PGA, 16-component multivectors.
// C[..., k] = sum_ij A[...,i] * B[...,j] * cayley[k,i,j]
// Cayley table rebuilt at COMPILE TIME (mirrors the reference Python), so the
// 256-term double loop constant-folds to the 192 nonzero +-1 fp32 FMAs.
//
// R2: no LDS, no barriers. Each thread owns one MV and loads it with 4
// dwordx4 at 64B lane stride; the 4 loads re-touch the same 64B segments
// across the q-loop, so L1 serves the "uncoalesced" fraction and HBM traffic
// stays at the 384MB logical floor. Removing the LDS stage kills the 6.2M
// conflict cycles, both syncthreads, and the 40KB/block occupancy cap.

namespace {

struct CayleyLUT {
    int idx[16][16];  // result component k for (i,j)
    int sgn[16][16];  // -1, 0, +1
};

constexpr CayleyLUT make_lut() {
    CayleyLUT L{};
    constexpr int MASK[16] = {0, 2, 4, 8, 1, 6, 10, 12, 3, 5, 9, 14, 7, 11, 13, 15};
    constexpr int SIGN[16] = {1, 1, 1, 1, 1, 1, 1, 1, -1, -1, -1, 1, 1, 1, 1, -1};
    for (int i = 0; i < 16; ++i) {
        for (int j = 0; j < 16; ++j) {
            L.idx[i][j] = 0;
            L.sgn[i][j] = 0;
            if (MASK[i] & MASK[j] & 1) continue;  // shared null e0 -> vanishes
            const int rm = MASK[i] ^ MASK[j];
            int k = 0;
            for (int t = 0; t < 16; ++t)
                if (MASK[t] == rm) k = t;
            int s = 1;
            for (int bit = 0; bit < 4; ++bit) {
                if ((MASK[i] >> bit) & 1) {
                    int lower = MASK[j] & ((1 << bit) - 1);
                    int c = 0;
                    for (int x = lower; x; x >>= 1) c += x & 1;
                    if (c & 1) s = -s;
                }
            }
            L.idx[i][j] = k;
            L.sgn[i][j] = SIGN[i] * SIGN[j] * s * SIGN[k];
        }
    }
    return L;
}

constexpr CayleyLUT LUT = make_lut();

__global__ __launch_bounds__(256) void gp_kernel(const float* __restrict__ A,
                                                 const float* __restrict__ B,
                                                 float* __restrict__ C,
                                                 long long n_mv) {
    const long long m = (long long)blockIdx.x * 256 + threadIdx.x;
    if (m >= n_mv) return;

    const float4* __restrict__ A4 = reinterpret_cast<const float4*>(A) + (m << 2);
    const float4* __restrict__ B4 = reinterpret_cast<const float4*>(B) + (m << 2);
    float4* __restrict__ C4 = reinterpret_cast<float4*>(C) + (m << 2);

    // Issue all 8 loads up front; fully unrolled -> static register indexing.
    float a[16], b[16];
#pragma unroll
    for (int q = 0; q < 4; ++q) {
        const float4 va = A4[q];
        const float4 vb = B4[q];
        a[4 * q + 0] = va.x; a[4 * q + 1] = va.y; a[4 * q + 2] = va.z; a[4 * q + 3] = va.w;
        b[4 * q + 0] = vb.x; b[4 * q + 1] = vb.y; b[4 * q + 2] = vb.z; b[4 * q + 3] = vb.w;
    }

    float c[16];
#pragma unroll
    for (int k = 0; k < 16; ++k) c[k] = 0.0f;
    // Fully unrolled; LUT is constexpr -> folds to 192 v_fma_f32 (sign via
    // free negate modifier on the consumer).
#pragma unroll
    for (int i = 0; i < 16; ++i) {
#pragma unroll
        for (int j = 0; j < 16; ++j) {
            const int s = LUT.sgn[i][j];
            if (s != 0) {
                const int k = LUT.idx[i][j];
                c[k] = fmaf(s > 0 ? a[i] : -a[i], b[j], c[k]);
            }
        }
    }

#pragma unroll
    for (int q = 0; q < 4; ++q) {
        float4 v;
        v.x = c[4 * q + 0]; v.y = c[4 * q + 1]; v.z = c[4 * q + 2]; v.w = c[4 * q + 3];
        C4[q] = v;
    }
}

}  // namespace

extern "C" void kernel_launch(void* const* d_in, const int* in_sizes, int n_in,
                              void* d_out, int out_size, void* d_ws, size_t ws_size,
                              hipStream_t stream) {
    const float* A = (const float*)d_in[0];
    const float* B = (const float*)d_in[1];
    float* C = (float*)d_out;
    const long long n_mv = (long long)in_sizes[0] / 16;
    const int nblocks = (int)((n_mv + 255) / 256);
    gp_kernel<<<nblocks, 256, 0, stream>>>(A, B, C, n_mv);
}

// Round 3
// 77.341 us; speedup vs baseline: 1.1317x; 1.1317x over previous
//
#include <hip/hip_runtime.h>

// Geometric product over 3D PGA, 16-component multivectors.
// C[..., k] = sum_ij A[...,i] * B[...,j] * cayley[k,i,j]
// Cayley table rebuilt at COMPILE TIME (mirrors the reference Python); the
// 16x16 double loop constant-folds to the 192 nonzero +-1 fp32 FMAs.
//
// R3: R1's coalesced-global + LDS-transpose structure, with a conflict-free
// XOR-swizzled LDS layout instead of PAD=20. Quad q of MV m lives at float
// offset m*16 + 4*(q^(m&3)); in both the staging (f-pattern) and compute
// (t-pattern) access orders, each group of 8 consecutive lanes covers 8
// distinct 4-bank groups = all 32 banks -> zero ds_*_b128 conflicts
// (R1 measured 6.2M conflict cycles). 32KB LDS -> 5 blocks/CU (was 4 at
// 40KB). Exact-fit fast path drops all tail guards (grid is exactly full
// for the 4*4096*128 harness shape).

namespace {

struct CayleyLUT {
    int idx[16][16];
    int sgn[16][16];
};

constexpr CayleyLUT make_lut() {
    CayleyLUT L{};
    constexpr int MASK[16] = {0, 2, 4, 8, 1, 6, 10, 12, 3, 5, 9, 14, 7, 11, 13, 15};
    constexpr int SIGN[16] = {1, 1, 1, 1, 1, 1, 1, 1, -1, -1, -1, 1, 1, 1, 1, -1};
    for (int i = 0; i < 16; ++i) {
        for (int j = 0; j < 16; ++j) {
            L.idx[i][j] = 0;
            L.sgn[i][j] = 0;
            if (MASK[i] & MASK[j] & 1) continue;  // shared null e0 -> vanishes
            const int rm = MASK[i] ^ MASK[j];
            int k = 0;
            for (int t = 0; t < 16; ++t)
                if (MASK[t] == rm) k = t;
            int s = 1;
            for (int bit = 0; bit < 4; ++bit) {
                if ((MASK[i] >> bit) & 1) {
                    int lower = MASK[j] & ((1 << bit) - 1);
                    int c = 0;
                    for (int x = lower; x; x >>= 1) c += x & 1;
                    if (c & 1) s = -s;
                }
            }
            L.idx[i][j] = k;
            L.sgn[i][j] = SIGN[i] * SIGN[j] * s * SIGN[k];
        }
    }
    return L;
}

constexpr CayleyLUT LUT = make_lut();

__device__ __forceinline__ int slot(int m, int q) {
    // Float offset of quad q of MV m in the swizzled LDS tile.
    return m * 16 + ((q ^ (m & 3)) << 2);
}

__device__ __forceinline__ void gp_compute(const float* a, const float* b, float* c) {
#pragma unroll
    for (int k = 0; k < 16; ++k) c[k] = 0.0f;
#pragma unroll
    for (int i = 0; i < 16; ++i) {
#pragma unroll
        for (int j = 0; j < 16; ++j) {
            const int s = LUT.sgn[i][j];
            if (s != 0) {
                const int k = LUT.idx[i][j];
                c[k] = fmaf(s > 0 ? a[i] : -a[i], b[j], c[k]);
            }
        }
    }
}

__global__ __launch_bounds__(256) void gp_kernel(const float* __restrict__ A,
                                                 const float* __restrict__ B,
                                                 float* __restrict__ C,
                                                 long long n_mv) {
    __shared__ float sA[256 * 16];  // 16 KiB
    __shared__ float sB[256 * 16];  // 16 KiB
    const int t = threadIdx.x;
    const long long base_mv = (long long)blockIdx.x * 256;
    const bool full = (base_mv + 256 <= n_mv);
    const int mv_here = full ? 256 : (int)(n_mv - base_mv);
    const int nf4 = mv_here * 4;

    const float4* __restrict__ A4 = reinterpret_cast<const float4*>(A) + base_mv * 4;
    const float4* __restrict__ B4 = reinterpret_cast<const float4*>(B) + base_mv * 4;
    float4* __restrict__ C4 = reinterpret_cast<float4*>(C) + base_mv * 4;

    // ---- stage in (coalesced float4 loads, swizzled LDS scatter) ----
    if (full) {
#pragma unroll
        for (int r = 0; r < 4; ++r) {
            const int f = t + 256 * r;
            const float4 va = A4[f];
            const float4 vb = B4[f];
            const int o = slot(f >> 2, f & 3);
            *reinterpret_cast<float4*>(&sA[o]) = va;
            *reinterpret_cast<float4*>(&sB[o]) = vb;
        }
    } else {
#pragma unroll
        for (int r = 0; r < 4; ++r) {
            const int f = t + 256 * r;
            if (f < nf4) {
                const float4 va = A4[f];
                const float4 vb = B4[f];
                const int o = slot(f >> 2, f & 3);
                *reinterpret_cast<float4*>(&sA[o]) = va;
                *reinterpret_cast<float4*>(&sB[o]) = vb;
            }
        }
    }
    __syncthreads();

    // ---- compute: thread t owns MV t of the tile ----
    if (full || t < mv_here) {
        float a[16], b[16];
#pragma unroll
        for (int q = 0; q < 4; ++q) {
            const int o = slot(t, q);
            const float4 va = *reinterpret_cast<const float4*>(&sA[o]);
            const float4 vb = *reinterpret_cast<const float4*>(&sB[o]);
            a[4 * q + 0] = va.x; a[4 * q + 1] = va.y; a[4 * q + 2] = va.z; a[4 * q + 3] = va.w;
            b[4 * q + 0] = vb.x; b[4 * q + 1] = vb.y; b[4 * q + 2] = vb.z; b[4 * q + 3] = vb.w;
        }
        float c[16];
        gp_compute(a, b, c);
        // Stage out into sA: thread t only touches row t (its own compute
        // input), so no barrier needed before these writes.
#pragma unroll
        for (int q = 0; q < 4; ++q) {
            float4 v;
            v.x = c[4 * q + 0]; v.y = c[4 * q + 1]; v.z = c[4 * q + 2]; v.w = c[4 * q + 3];
            *reinterpret_cast<float4*>(&sA[slot(t, q)]) = v;
        }
    }
    __syncthreads();

    // ---- stage out (swizzled LDS gather, coalesced float4 stores) ----
    if (full) {
#pragma unroll
        for (int r = 0; r < 4; ++r) {
            const int f = t + 256 * r;
            C4[f] = *reinterpret_cast<const float4*>(&sA[slot(f >> 2, f & 3)]);
        }
    } else {
#pragma unroll
        for (int r = 0; r < 4; ++r) {
            const int f = t + 256 * r;
            if (f < nf4) {
                C4[f] = *reinterpret_cast<const float4*>(&sA[slot(f >> 2, f & 3)]);
            }
        }
    }
}

}  // namespace

extern "C" void kernel_launch(void* const* d_in, const int* in_sizes, int n_in,
                              void* d_out, int out_size, void* d_ws, size_t ws_size,
                              hipStream_t stream) {
    const float* A = (const float*)d_in[0];
    const float* B = (const float*)d_in[1];
    float* C = (float*)d_out;
    const long long n_mv = (long long)in_sizes[0] / 16;
    const int nblocks = (int)((n_mv + 255) / 256);
    gp_kernel<<<nblocks, 256, 0, stream>>>(A, B, C, n_mv);
}

// Round 4
// 76.934 us; speedup vs baseline: 1.1377x; 1.0053x over previous
//
#include <hip/hip_runtime.h>

// Geometric product over 3D PGA, 16-component multivectors.
// C[..., k] = sum_ij A[...,i] * B[...,j] * cayley[k,i,j]
// Cayley table rebuilt at COMPILE TIME (mirrors the reference Python); the
// 16x16 double loop constant-folds to the 192 nonzero +-1 fp32 FMAs.
//
// R4: fix the LDS swizzle. R3's slot(m,q)=m*16+((q^(m&3))<<2) left the
// COMPUTE access 2-way conflicted: for fixed q, lanes t and t+4 share a
// 4-bank group (t*16 mod 32 depends only on t&1; q^(t&3) has period 4)
// -> measured 4.2M conflict cycles. New swizzle uses bit 1..2 of m:
//   slot(m,q) = m*16 + ((q ^ ((m>>1)&3)) << 2)
// Enumerated check, 8-lane phases:
//   stage pattern (m=f>>2,q=f&3): groups {0..3} from even m, {4..7} odd  OK
//   compute pattern (m=t, fixed q): even lanes q^{0,1,2,3}, odd +4       OK
// All ds_*_b128 phases now hit 8 distinct 4-bank groups = conflict-free.

namespace {

struct CayleyLUT {
    int idx[16][16];
    int sgn[16][16];
};

constexpr CayleyLUT make_lut() {
    CayleyLUT L{};
    constexpr int MASK[16] = {0, 2, 4, 8, 1, 6, 10, 12, 3, 5, 9, 14, 7, 11, 13, 15};
    constexpr int SIGN[16] = {1, 1, 1, 1, 1, 1, 1, 1, -1, -1, -1, 1, 1, 1, 1, -1};
    for (int i = 0; i < 16; ++i) {
        for (int j = 0; j < 16; ++j) {
            L.idx[i][j] = 0;
            L.sgn[i][j] = 0;
            if (MASK[i] & MASK[j] & 1) continue;  // shared null e0 -> vanishes
            const int rm = MASK[i] ^ MASK[j];
            int k = 0;
            for (int t = 0; t < 16; ++t)
                if (MASK[t] == rm) k = t;
            int s = 1;
            for (int bit = 0; bit < 4; ++bit) {
                if ((MASK[i] >> bit) & 1) {
                    int lower = MASK[j] & ((1 << bit) - 1);
                    int c = 0;
                    for (int x = lower; x; x >>= 1) c += x & 1;
                    if (c & 1) s = -s;
                }
            }
            L.idx[i][j] = k;
            L.sgn[i][j] = SIGN[i] * SIGN[j] * s * SIGN[k];
        }
    }
    return L;
}

constexpr CayleyLUT LUT = make_lut();

__device__ __forceinline__ int slot(int m, int q) {
    // Float offset of quad q of MV m in the swizzled LDS tile.
    return m * 16 + ((q ^ ((m >> 1) & 3)) << 2);
}

__device__ __forceinline__ void gp_compute(const float* a, const float* b, float* c) {
#pragma unroll
    for (int k = 0; k < 16; ++k) c[k] = 0.0f;
#pragma unroll
    for (int i = 0; i < 16; ++i) {
#pragma unroll
        for (int j = 0; j < 16; ++j) {
            const int s = LUT.sgn[i][j];
            if (s != 0) {
                const int k = LUT.idx[i][j];
                c[k] = fmaf(s > 0 ? a[i] : -a[i], b[j], c[k]);
            }
        }
    }
}

__global__ __launch_bounds__(256) void gp_kernel(const float* __restrict__ A,
                                                 const float* __restrict__ B,
                                                 float* __restrict__ C,
                                                 long long n_mv) {
    __shared__ float sA[256 * 16];  // 16 KiB
    __shared__ float sB[256 * 16];  // 16 KiB
    const int t = threadIdx.x;
    const long long base_mv = (long long)blockIdx.x * 256;
    const bool full = (base_mv + 256 <= n_mv);
    const int mv_here = full ? 256 : (int)(n_mv - base_mv);
    const int nf4 = mv_here * 4;

    const float4* __restrict__ A4 = reinterpret_cast<const float4*>(A) + base_mv * 4;
    const float4* __restrict__ B4 = reinterpret_cast<const float4*>(B) + base_mv * 4;
    float4* __restrict__ C4 = reinterpret_cast<float4*>(C) + base_mv * 4;

    // ---- stage in (coalesced float4 loads, swizzled LDS scatter) ----
    if (full) {
#pragma unroll
        for (int r = 0; r < 4; ++r) {
            const int f = t + 256 * r;
            const float4 va = A4[f];
            const float4 vb = B4[f];
            const int o = slot(f >> 2, f & 3);
            *reinterpret_cast<float4*>(&sA[o]) = va;
            *reinterpret_cast<float4*>(&sB[o]) = vb;
        }
    } else {
#pragma unroll
        for (int r = 0; r < 4; ++r) {
            const int f = t + 256 * r;
            if (f < nf4) {
                const float4 va = A4[f];
                const float4 vb = B4[f];
                const int o = slot(f >> 2, f & 3);
                *reinterpret_cast<float4*>(&sA[o]) = va;
                *reinterpret_cast<float4*>(&sB[o]) = vb;
            }
        }
    }
    __syncthreads();

    // ---- compute: thread t owns MV t of the tile ----
    if (full || t < mv_here) {
        float a[16], b[16];
#pragma unroll
        for (int q = 0; q < 4; ++q) {
            const int o = slot(t, q);
            const float4 va = *reinterpret_cast<const float4*>(&sA[o]);
            const float4 vb = *reinterpret_cast<const float4*>(&sB[o]);
            a[4 * q + 0] = va.x; a[4 * q + 1] = va.y; a[4 * q + 2] = va.z; a[4 * q + 3] = va.w;
            b[4 * q + 0] = vb.x; b[4 * q + 1] = vb.y; b[4 * q + 2] = vb.z; b[4 * q + 3] = vb.w;
        }
        float c[16];
        gp_compute(a, b, c);
        // Stage out into sA: thread t only touches row t (its own compute
        // input), so no barrier needed before these writes.
#pragma unroll
        for (int q = 0; q < 4; ++q) {
            float4 v;
            v.x = c[4 * q + 0]; v.y = c[4 * q + 1]; v.z = c[4 * q + 2]; v.w = c[4 * q + 3];
            *reinterpret_cast<float4*>(&sA[slot(t, q)]) = v;
        }
    }
    __syncthreads();

    // ---- stage out (swizzled LDS gather, coalesced float4 stores) ----
    if (full) {
#pragma unroll
        for (int r = 0; r < 4; ++r) {
            const int f = t + 256 * r;
            C4[f] = *reinterpret_cast<const float4*>(&sA[slot(f >> 2, f & 3)]);
        }
    } else {
#pragma unroll
        for (int r = 0; r < 4; ++r) {
            const int f = t + 256 * r;
            if (f < nf4) {
                C4[f] = *reinterpret_cast<const float4*>(&sA[slot(f >> 2, f & 3)]);
            }
        }
    }
}

}  // namespace

extern "C" void kernel_launch(void* const* d_in, const int* in_sizes, int n_in,
                              void* d_out, int out_size, void* d_ws, size_t ws_size,
                              hipStream_t stream) {
    const float* A = (const float*)d_in[0];
    const float* B = (const float*)d_in[1];
    float* C = (float*)d_out;
    const long long n_mv = (long long)in_sizes[0] / 16;
    const int nblocks = (int)((n_mv + 255) / 256);
    gp_kernel<<<nblocks, 256, 0, stream>>>(A, B, C, n_mv);
}